// Round 3
// baseline (719.860 us; speedup 1.0000x reference)
//
#include <hip/hip_runtime.h>

// Problem constants
#define NB 32
#define NT 1024
#define ND 512
#define NG 256
#define NE 8
#define NV 8192
#define NROW (NB * NT)   // 32768 output rows

// ---- workspace layout (bytes) ----
#define XBF_BYTES   (33554432)   // NB*NT*ND bf16
#define WT_BYTES    (67108864)   // NE*NV*ND bf16 transposed [e][v][d]
#define PSUM_BYTES  (8388608)    // >= NCT x 32768 rows f32 partial sumexp
#define TL_BYTES    (131072)     // NB*NT f32 target logits

// ---- GEMM geometry: 256x256 tile, BK=64, 8 waves (2Mx4N), 512 threads ----
#define BM2 256
#define BN2 256
#define NCT (NV / BN2)           // 32 column tiles

typedef float f32x4 __attribute__((ext_vector_type(4)));
typedef __bf16 bf16x8 __attribute__((ext_vector_type(8)));
typedef unsigned short ushort8_v __attribute__((ext_vector_type(8)));
typedef unsigned int u32_g __attribute__((address_space(1)));
typedef unsigned int u32_l __attribute__((address_space(3)));
typedef unsigned short ushort_t;

__device__ __forceinline__ void g2l16(void* lds, const void* g) {
    // async global->LDS, 16B per lane; LDS dest = wave-uniform base + lane*16
    __builtin_amdgcn_global_load_lds((const u32_g*)g, (u32_l*)lds, 16, 0, 0);
}

__device__ __forceinline__ unsigned short f2bf(float f) {
    unsigned int u = __float_as_uint(f);
    unsigned int r = (u + 0x7fffu + ((u >> 16) & 1u)) >> 16; // RNE
    return (unsigned short)r;
}

// ---------------- K1: router (tiny) ----------------
__global__ void k_router(const float* __restrict__ gate, const float* __restrict__ Wg,
                         const float* __restrict__ bg, float* __restrict__ out,
                         int* __restrict__ assign, int* __restrict__ counts) {
    __shared__ float lg[NB][NE];
    __shared__ int lam[NB];
    int tid = threadIdx.x;                 // 256 threads: one per (b,e)
    int b = tid >> 3, e = tid & 7;
    float acc = bg[e];
    const float* gr = gate + b * NG;
    for (int g = 0; g < NG; ++g) acc = fmaf(gr[g], Wg[g * NE + e], acc);
    lg[b][e] = acc;
    __syncthreads();
    if (tid < NB) {
        float mx = lg[tid][0]; int am = 0;
        for (int j = 1; j < NE; ++j) { float v = lg[tid][j]; if (v > mx) { mx = v; am = j; } }
        float den = 0.f, ex[NE];
        for (int j = 0; j < NE; ++j) { ex[j] = __expf(lg[tid][j] - mx); den += ex[j]; }
        float inv = 1.f / den;
        for (int j = 0; j < NE; ++j) out[1 + NB + tid * NE + j] = ex[j] * inv; // probs
        out[1 + tid] = (float)am;                                             // assignments
        assign[tid] = am;
        lam[tid] = am;
    }
    __syncthreads();
    if (tid == 0) {
        int c[NE] = {0,0,0,0,0,0,0,0};
        for (int i = 0; i < NB; ++i) c[lam[i]]++;
        for (int j = 0; j < NE; ++j) counts[j] = c[j];
        out[0] = 0.f;
    }
}

// ---------------- K2: convert X fp32 -> bf16 ----------------
__global__ void k_convx(const float4* __restrict__ in, ushort_t* __restrict__ out, int n4) {
    int i = blockIdx.x * blockDim.x + threadIdx.x;
    int stride = gridDim.x * blockDim.x;
    for (; i < n4; i += stride) {
        float4 v = in[i];
        ushort4 o;
        o.x = f2bf(v.x); o.y = f2bf(v.y); o.z = f2bf(v.z); o.w = f2bf(v.w);
        ((ushort4*)out)[i] = o;
    }
}

// ---------------- K3: transpose+convert We[e][d][v] -> Wt[e][v][d] bf16 ----------------
// 64x64 tiles, float4 reads (16B/lane), ushort8 writes (16B/lane, 128B/row).
// LDS columns XOR-rotated by (d>>3) so the strided read-back (8 lanes share v,
// d-chunks 0..56) hits 8 distinct banks (4*((v>>2)^t) distinct mod 32).
__global__ void k_transw(const float* __restrict__ We, ushort_t* __restrict__ Wt) {
    __shared__ float tile[64][68];   // 17.4 KB; row stride 68 keeps float4 alignment
    int e = blockIdx.z, d0 = blockIdx.y * 64, v0 = blockIdx.x * 64;
    int tid = threadIdx.x;
    const float* src = We + (size_t)e * ND * NV + (size_t)d0 * NV + v0;
    int dr = tid >> 4;          // 0..15
    int c4 = tid & 15;          // float4 column index
#pragma unroll
    for (int j = 0; j < 4; ++j) {
        int d = dr + 16 * j;
        float4 v = *(const float4*)(src + (size_t)d * NV + c4 * 4);
        *(float4*)&tile[d][((c4 ^ (d >> 3)) & 15) * 4] = v;
    }
    __syncthreads();
    ushort_t* dst = Wt + (size_t)e * NV * ND + (size_t)v0 * ND + d0;
    int vr = tid >> 3;          // 0..31 (+32 on pass 2)
    int t8 = tid & 7;           // d-chunk index; d = t8*8 + i, (d>>3) == t8
#pragma unroll
    for (int j = 0; j < 2; ++j) {
        int v = vr + 32 * j;
        ushort8_v o;
#pragma unroll
        for (int i = 0; i < 8; ++i)
            o[i] = f2bf(tile[t8 * 8 + i][(((v >> 2) ^ t8) & 15) * 4 + (v & 3)]);
        *(ushort8_v*)(dst + (size_t)v * ND + t8 * 8) = o;
    }
}

// ---------------- K4: persistent fused GEMM + exp partial-sum ----------------
// grid = 256 blocks (1/CU), each processes 16 tiles of 256x256. The steady-state
// stage schedule extends across tile boundaries unchanged: at kt6/kt7 the
// STB(kt+2)/STA(kt+1) slots stage the NEXT tile's kt0/kt1 (identical buffer
// parity), so the vmcnt(4) pipeline never drains except at the very end.
// Epilogue (exp2 partial-sums) runs while next-tile loads are in flight.
//
// LDS (132 KiB static): dbuf p at p*65536 { A[256][64] bf16 ; B at +32768 },
// lws epilogue scratch at 131072. T2 swizzle: linear global_load_lds dest,
// source 16B-slot pre-XOR'd by row&7, same XOR on ds_read.

#define BAR_MID() do { \
    asm volatile("" ::: "memory"); \
    __builtin_amdgcn_s_barrier(); \
    asm volatile("s_waitcnt lgkmcnt(0)" ::: "memory"); \
    __builtin_amdgcn_sched_barrier(0); } while (0)

#define BAR_END() do { \
    asm volatile("" ::: "memory"); \
    __builtin_amdgcn_s_barrier(); \
    asm volatile("" ::: "memory"); } while (0)

#define MFMA_QUAD(MH, NH) do { \
    __builtin_amdgcn_s_setprio(1); \
    _Pragma("unroll") \
    for (int m_ = 0; m_ < 4; ++m_) \
      _Pragma("unroll") \
      for (int n_ = 0; n_ < 2; ++n_) \
        _Pragma("unroll") \
        for (int ks_ = 0; ks_ < 2; ++ks_) \
          acc[(MH) * 4 + m_][(NH) * 2 + n_] = __builtin_amdgcn_mfma_f32_16x16x32_bf16( \
              af[m_][ks_], bfr[(NH) * 2 + n_][ks_], acc[(MH) * 4 + m_][(NH) * 2 + n_], 0, 0, 0); \
    __builtin_amdgcn_s_setprio(0); } while (0)

__global__ __launch_bounds__(512, 2)
void k_gemm(const ushort_t* __restrict__ Xbf, const ushort_t* __restrict__ Wtbf,
            const float* __restrict__ be, const int* __restrict__ assign,
            float* __restrict__ psum) {
    __shared__ alignas(16) char smem[135168];
    float* lws = (float*)(smem + 131072);

    const int tid  = threadIdx.x;
    const int wid  = tid >> 6, lane = tid & 63;
    const int q = lane >> 4, ln = lane & 15;
    const int wr = wid >> 2, wc = wid & 3;

    const int pid  = blockIdx.x;           // 0..255 persistent
    const int xcd  = pid & 7;              // bid%8 -> XCD (T1)
    const int base = pid >> 3;             // 0..31

    // lane-varying base + per-tile scalar offsets (keeps VGPR budget)
    const int rquo = tid >> 3;                         // 0..63
    const int scol = ((tid & 7) ^ (rquo & 7)) << 3;    // source-side swizzle
    const ushort_t* gAl = Xbf  + (size_t)rquo * ND + scol;
    const ushort_t* gBl = Wtbf + (size_t)rquo * ND + scol;
    char* ldsW = smem + wid * 1024;                    // wave-uniform dest base
    const int axor = ln & 7;                           // read-side XOR

    f32x4 acc[8][4];

#define STA(OFF, KT, BP, H) do { \
    char* d_ = ldsW + (BP) * 65536 + (H) * 16384; \
    const ushort_t* g_ = gAl + (OFF) + (H) * 128 * ND + (KT) * 64; \
    g2l16(d_, g_); g2l16(d_ + 8192, g_ + (size_t)64 * ND); } while (0)

#define STB(OFF, KT, BP, H) do { \
    char* d_ = ldsW + (BP) * 65536 + 32768 + (H) * 16384; \
    const ushort_t* g_ = gBl + (OFF) + (H) * 128 * ND + (KT) * 64; \
    g2l16(d_, g_); g2l16(d_ + 8192, g_ + (size_t)64 * ND); } while (0)

#define RDA(BP, MF, KS) \
    (*(const bf16x8*)(smem + (BP) * 65536 + wr * 16384 + \
                      ((MF) * 16 + ln) * 128 + ((((KS) * 4 + q) ^ axor) << 4)))

#define RDB(BP, NF, KS) \
    (*(const bf16x8*)(smem + (BP) * 65536 + 32768 + (wc >> 1) * 16384 + \
                      (((wc & 1) * 64 + (NF) * 16 + ln) * 128) + ((((KS) * 4 + q) ^ axor) << 4)))

    // ---- prologue (tile 0 only): kt0 fully + B halves of kt1 ----
    {
        int wg0 = (xcd << 9) | base;
        int rt0 = wg0 & 127, ct0 = wg0 >> 7;
        int e0  = assign[rt0 >> 2];
        int oA  = rt0 * (BM2 * ND);
        int oB  = (e0 * NV + ct0 * BN2) * ND;
        STB(oB, 0, 0, 0); STB(oB, 0, 0, 1); STA(oA, 0, 0, 0); STA(oA, 0, 0, 1);
        STB(oB, 1, 1, 0); STB(oB, 1, 1, 1);
        asm volatile("s_waitcnt vmcnt(4)" ::: "memory");
        __builtin_amdgcn_s_barrier();
        asm volatile("" ::: "memory");
    }

    bf16x8 af[4][2];    // current A quadrant-half
    bf16x8 bfr[4][2];   // all 4 B n-frags of current K-tile

#pragma unroll 1
    for (int tt = 0; tt < 16; ++tt) {
        // current tile coords / offsets (all wave-uniform scalars)
        const int wg  = (xcd << 9) | (base + 32 * tt);
        const int ct  = wg >> 7, rt = wg & 127;
        const int e   = assign[rt >> 2];
        const int oAc = rt * (BM2 * ND);
        const int oBc = (e * NV + ct * BN2) * ND;
        const size_t eV = (size_t)e * NV;
        // next tile offsets (used only at kt>=6; index math safe for tt==15)
        const int wgn = (xcd << 9) | ((base + 32 * (tt + 1)) & 511);
        const int ctn = wgn >> 7, rtn = wgn & 127;
        const int en  = assign[rtn >> 2];
        const int oAn = rtn * (BM2 * ND);
        const int oBn = (en * NV + ctn * BN2) * ND;
        const bool more = (tt < 15);

#pragma unroll
        for (int i = 0; i < 8; ++i)
#pragma unroll
            for (int j = 0; j < 4; ++j) acc[i][j] = (f32x4){0.f, 0.f, 0.f, 0.f};

#pragma unroll
        for (int kt = 0; kt < 8; ++kt) {
            const int p = kt & 1, np = p ^ 1;

            // ---- phase 1: quadrant (0,0) ----
#pragma unroll
            for (int m = 0; m < 4; ++m) { af[m][0] = RDA(p, m, 0); af[m][1] = RDA(p, m, 1); }
#pragma unroll
            for (int n = 0; n < 2; ++n) { bfr[n][0] = RDB(p, n, 0); bfr[n][1] = RDB(p, n, 1); }
            if (kt < 7)      STA(oAc, kt + 1, np, 0);
            else if (more)   STA(oAn, 0, np, 0);
            BAR_MID();
            MFMA_QUAD(0, 0);
            BAR_END();

            // ---- phase 2: quadrant (0,1) ----
#pragma unroll
            for (int n = 0; n < 2; ++n) { bfr[2 + n][0] = RDB(p, 2 + n, 0); bfr[2 + n][1] = RDB(p, 2 + n, 1); }
            if (kt < 7)      STA(oAc, kt + 1, np, 1);
            else if (more)   STA(oAn, 0, np, 1);
            BAR_MID();
            MFMA_QUAD(0, 1);
            BAR_END();

            // ---- phase 3: quadrant (1,1) ----
#pragma unroll
            for (int m = 0; m < 4; ++m) { af[m][0] = RDA(p, 4 + m, 0); af[m][1] = RDA(p, 4 + m, 1); }
            if (kt < 6)      STB(oBc, kt + 2, p, 0);
            else if (more)   STB(oBn, kt - 6, p, 0);
            BAR_MID();
            MFMA_QUAD(1, 1);
            BAR_END();

            // ---- phase 4: quadrant (1,0); K-tile boundary wait ----
            if (kt < 6)      STB(oBc, kt + 2, p, 1);
            else if (more)   STB(oBn, kt - 6, p, 1);
            BAR_MID();
            MFMA_QUAD(1, 0);
            if (kt < 6 || more) { asm volatile("s_waitcnt vmcnt(4)" ::: "memory"); }
            else if (kt == 6)   { asm volatile("s_waitcnt vmcnt(0)" ::: "memory"); }
            BAR_END();
        }

        // ---- epilogue: per-row partial sum of exp(logit + bias), 256 cols ----
        // (no __syncthreads here: avoid implicit vmcnt(0) drain of in-flight
        //  next-tile staging; lgkmcnt(0)+s_barrier is sufficient for lws)
        const float LOG2E = 1.44269504088896f;
        float partial[32];
#pragma unroll
        for (int i = 0; i < 32; ++i) partial[i] = 0.f;
#pragma unroll
        for (int nf = 0; nf < 4; ++nf) {
            int col = (ct << 8) + (wc << 6) + nf * 16 + ln;
            float eb = be[eV + col] * LOG2E;
#pragma unroll
            for (int mf = 0; mf < 8; ++mf)
#pragma unroll
                for (int r = 0; r < 4; ++r)
                    partial[mf * 4 + r] += exp2f(fmaf(acc[mf][nf][r], LOG2E, eb));
        }
#pragma unroll
        for (int i = 0; i < 32; ++i) {
            float pv = partial[i];
            pv += __shfl_xor(pv, 1); pv += __shfl_xor(pv, 2);
            pv += __shfl_xor(pv, 4); pv += __shfl_xor(pv, 8);
            partial[i] = pv;
        }
        if (ln == 0) {
#pragma unroll
            for (int mf = 0; mf < 8; ++mf)
#pragma unroll
                for (int r = 0; r < 4; ++r)
                    lws[wid * 128 + mf * 16 + q * 4 + r] = partial[mf * 4 + r];
        }
        asm volatile("s_waitcnt lgkmcnt(0)" ::: "memory");
        __builtin_amdgcn_s_barrier();
        asm volatile("" ::: "memory");
        if (tid < 256) {
            int wrh = tid >> 7, idx = tid & 127;
            float s = lws[(wrh * 4 + 0) * 128 + idx] + lws[(wrh * 4 + 1) * 128 + idx]
                    + lws[(wrh * 4 + 2) * 128 + idx] + lws[(wrh * 4 + 3) * 128 + idx];
            psum[(size_t)ct * NROW + rt * 256 + tid] = s;
        }
        BAR_END();   // lws safe: next write is a full K-loop away
    }
#undef STA
#undef STB
#undef RDA
#undef RDB
}

// ---------------- K5: target logit (no atomics) ----------------
__global__ void k_target(const ushort_t* __restrict__ Xbf, const ushort_t* __restrict__ Wtbf,
                         const float* __restrict__ be, const int* __restrict__ assign,
                         const int* __restrict__ tgt, float* __restrict__ tl) {
    int wave = threadIdx.x >> 6, lane = threadIdx.x & 63;
    int wg = blockIdx.x * 4 + wave;       // one wave per (b,t)
    int b = wg >> 10, t = wg & 1023;
    int e = assign[b];
    int id = tgt[b * NT + t];
    const bf16x8 xv = *(const bf16x8*)(Xbf + (size_t)(b * NT + t) * ND + lane * 8);
    const bf16x8 wv = *(const bf16x8*)(Wtbf + ((size_t)e * NV + id) * ND + lane * 8);
    float s = 0.f;
#pragma unroll
    for (int i = 0; i < 8; ++i) s = fmaf((float)xv[i], (float)wv[i], s);
    for (int off = 32; off; off >>= 1) s += __shfl_down(s, off);
    if (lane == 0) tl[b * NT + t] = s + be[(size_t)e * NV + id];
}

// ---------------- K6: reduce psum -> nll[b] ----------------
__global__ void k_loss(const float* __restrict__ psum, const float* __restrict__ tl,
                       float* __restrict__ nll) {
    int b = blockIdx.x, tid = threadIdx.x;   // 32 blocks x 256 threads
    float acc = 0.f;
#pragma unroll
    for (int j = 0; j < 4; ++j) {
        int t = j * 256 + tid;
        float s = 0.f;
        for (int ct = 0; ct < NCT; ++ct) s += psum[(size_t)ct * NROW + b * NT + t];
        acc += __logf(s) - tl[b * NT + t];
    }
    // block reduce 256 -> 1
    __shared__ float red[4];
    for (int off = 32; off; off >>= 1) acc += __shfl_down(acc, off);
    if ((tid & 63) == 0) red[tid >> 6] = acc;
    __syncthreads();
    if (tid == 0) nll[b] = red[0] + red[1] + red[2] + red[3];
}

// ---------------- K7: final combine ----------------
__global__ void k_final(const float* __restrict__ nll_sum, const int* __restrict__ assign,
                        const int* __restrict__ counts, float* __restrict__ out) {
    int tid = threadIdx.x; // 64 threads, one wave
    float contrib = 0.f;
    if (tid < NB) {
        float ce = nll_sum[tid] * (1.0f / (float)NT);
        contrib = ce / (float)counts[assign[tid]];
    }
    for (int off = 32; off; off >>= 1) contrib += __shfl_down(contrib, off);
    if (tid == 0) out[0] = contrib;
}

extern "C" void kernel_launch(void* const* d_in, const int* in_sizes, int n_in,
                              void* d_out, int out_size, void* d_ws, size_t ws_size,
                              hipStream_t stream) {
    const float* gate = (const float*)d_in[0];
    const float* X    = (const float*)d_in[1];
    const float* Wg   = (const float*)d_in[2];
    const float* bg   = (const float*)d_in[3];
    const float* We   = (const float*)d_in[4];
    const float* be   = (const float*)d_in[5];
    const int*   tgt  = (const int*)d_in[6];
    float* out = (float*)d_out;

    char* ws = (char*)d_ws;
    ushort_t* Xbf  = (ushort_t*)ws;
    ushort_t* Wtbf = (ushort_t*)(ws + XBF_BYTES);
    float*    psum = (float*)(ws + XBF_BYTES + WT_BYTES);
    float*    tl   = (float*)(ws + XBF_BYTES + WT_BYTES + PSUM_BYTES);
    int*      assign = (int*)(ws + XBF_BYTES + WT_BYTES + PSUM_BYTES + TL_BYTES);
    int*      counts = assign + 32;
    float*    nll    = (float*)(assign + 64);

    k_router<<<1, 256, 0, stream>>>(gate, Wg, bg, out, assign, counts);
    k_convx<<<4096, 256, 0, stream>>>((const float4*)X, Xbf, NB * NT * ND / 4);
    k_transw<<<dim3(NV / 64, ND / 64, NE), 256, 0, stream>>>(We, Wtbf);
    k_gemm<<<256, 512, 0, stream>>>(Xbf, Wtbf, be, assign, psum);
    k_target<<<NB * NT / 4, 256, 0, stream>>>(Xbf, Wtbf, be, assign, tgt, tl);
    k_loss<<<NB, 256, 0, stream>>>(psum, tl, nll);
    k_final<<<1, 64, 0, stream>>>(nll, assign, counts, out);
}

// Round 4
// 608.419 us; speedup vs baseline: 1.1832x; 1.1832x over previous
//
#include <hip/hip_runtime.h>

// Problem constants
#define NB 32
#define NT 1024
#define ND 512
#define NG 256
#define NE 8
#define NV 8192
#define NROW (NB * NT)   // 32768 output rows

// ---- workspace layout (bytes) ----
#define XBF_BYTES   (33554432)   // NB*NT*ND bf16
#define WT_BYTES    (67108864)   // NE*NV*ND bf16 transposed [e][v][d]
#define PSUM_BYTES  (8388608)    // >= NCT x 32768 rows f32 partial sumexp
#define TL_BYTES    (131072)     // NB*NT f32 target logits

// ---- GEMM geometry: 256x256 tile, BK=64, 8 waves (2Mx4N), 512 threads ----
#define BM2 256
#define BN2 256
#define NCT (NV / BN2)           // 32 column tiles

typedef float f32x4 __attribute__((ext_vector_type(4)));
typedef __bf16 bf16x8 __attribute__((ext_vector_type(8)));
typedef unsigned short ushort8_v __attribute__((ext_vector_type(8)));
typedef unsigned int u32_g __attribute__((address_space(1)));
typedef unsigned int u32_l __attribute__((address_space(3)));
typedef unsigned short ushort_t;

__device__ __forceinline__ void g2l16(void* lds, const void* g) {
    // async global->LDS, 16B per lane; LDS dest = wave-uniform base + lane*16
    __builtin_amdgcn_global_load_lds((const u32_g*)g, (u32_l*)lds, 16, 0, 0);
}

__device__ __forceinline__ unsigned short f2bf(float f) {
    unsigned int u = __float_as_uint(f);
    unsigned int r = (u + 0x7fffu + ((u >> 16) & 1u)) >> 16; // RNE
    return (unsigned short)r;
}

// ---------------- K2: convert X fp32 -> bf16 (+ router in block 0) ----------------
__global__ void k_convx(const float4* __restrict__ in, ushort_t* __restrict__ out4, int n4,
                        const float* __restrict__ gate, const float* __restrict__ Wg,
                        const float* __restrict__ bg, float* __restrict__ out,
                        int* __restrict__ assign, int* __restrict__ counts) {
    int tid = threadIdx.x;
    if (blockIdx.x == 0) {
        // ---- router: 256 threads, one per (b,e) ----
        __shared__ float lg[NB][NE];
        __shared__ int lam[NB];
        int b = tid >> 3, e = tid & 7;
        float acc = bg[e];
        const float* gr = gate + b * NG;
        for (int g = 0; g < NG; ++g) acc = fmaf(gr[g], Wg[g * NE + e], acc);
        lg[b][e] = acc;
        __syncthreads();
        if (tid < NB) {
            float mx = lg[tid][0]; int am = 0;
            for (int j = 1; j < NE; ++j) { float v = lg[tid][j]; if (v > mx) { mx = v; am = j; } }
            float den = 0.f, ex[NE];
            for (int j = 0; j < NE; ++j) { ex[j] = __expf(lg[tid][j] - mx); den += ex[j]; }
            float inv = 1.f / den;
            for (int j = 0; j < NE; ++j) out[1 + NB + tid * NE + j] = ex[j] * inv; // probs
            out[1 + tid] = (float)am;                                             // assignments
            assign[tid] = am;
            lam[tid] = am;
        }
        __syncthreads();
        if (tid == 0) {
            int c[NE] = {0,0,0,0,0,0,0,0};
            for (int i = 0; i < NB; ++i) c[lam[i]]++;
            for (int j = 0; j < NE; ++j) counts[j] = c[j];
            out[0] = 0.f;   // k_loss atomicAdds into this
        }
    }
    int i = blockIdx.x * blockDim.x + tid;
    int stride = gridDim.x * blockDim.x;
    for (; i < n4; i += stride) {
        float4 v = in[i];
        ushort4 o;
        o.x = f2bf(v.x); o.y = f2bf(v.y); o.z = f2bf(v.z); o.w = f2bf(v.w);
        ((ushort4*)out4)[i] = o;
    }
}

// ---------------- K3: transpose+convert We[e][d][v] -> Wt[e][v][d] bf16 ----------------
// 64x64 tiles, float4 reads (16B/lane), ushort8 writes (16B/lane, 128B/row).
// LDS columns XOR-rotated by (d>>3) so the strided read-back (8 lanes share v,
// d-chunks 0..56) hits 8 distinct banks.
__global__ void k_transw(const float* __restrict__ We, ushort_t* __restrict__ Wt) {
    __shared__ float tile[64][68];   // row stride 68 keeps float4 alignment
    int e = blockIdx.z, d0 = blockIdx.y * 64, v0 = blockIdx.x * 64;
    int tid = threadIdx.x;
    const float* src = We + (size_t)e * ND * NV + (size_t)d0 * NV + v0;
    int dr = tid >> 4;          // 0..15
    int c4 = tid & 15;          // float4 column index
#pragma unroll
    for (int j = 0; j < 4; ++j) {
        int d = dr + 16 * j;
        float4 v = *(const float4*)(src + (size_t)d * NV + c4 * 4);
        *(float4*)&tile[d][((c4 ^ (d >> 3)) & 15) * 4] = v;
    }
    __syncthreads();
    ushort_t* dst = Wt + (size_t)e * NV * ND + (size_t)v0 * ND + d0;
    int vr = tid >> 3;          // 0..31 (+32 on pass 2)
    int t8 = tid & 7;           // d-chunk index; d = t8*8 + i, (d>>3) == t8
#pragma unroll
    for (int j = 0; j < 2; ++j) {
        int v = vr + 32 * j;
        ushort8_v o;
#pragma unroll
        for (int i = 0; i < 8; ++i)
            o[i] = f2bf(tile[t8 * 8 + i][(((v >> 2) ^ t8) & 15) * 4 + (v & 3)]);
        *(ushort8_v*)(dst + (size_t)v * ND + t8 * 8) = o;
    }
}

// ---------------- K4: fused GEMM + exp partial-sum + target-logit extract ----------------
// R1-verified 256x256 / BK=64 / 8-wave / 4-quadrant-phase pipeline (T1+T2+T3/T4+T5).
// One tile per block, grid 4096 (16 generations). Epilogue additionally extracts
// logits[row][tgt[row]] for rows whose target column lies in this ct tile
// (exactly one block per row globally) -> replaces the k_target kernel.
//
// LDS (133 KiB): dbuf p at p*65536 { A[256][64] bf16 ; B at +32768 },
// lws at 131072 (4 KB), lt (256 targets) at 135168 (1 KB).

#define BAR_MID() do { \
    asm volatile("" ::: "memory"); \
    __builtin_amdgcn_s_barrier(); \
    asm volatile("s_waitcnt lgkmcnt(0)" ::: "memory"); \
    __builtin_amdgcn_sched_barrier(0); } while (0)

#define BAR_END() do { \
    asm volatile("" ::: "memory"); \
    __builtin_amdgcn_s_barrier(); \
    asm volatile("" ::: "memory"); } while (0)

#define MFMA_QUAD(MH, NH) do { \
    __builtin_amdgcn_s_setprio(1); \
    _Pragma("unroll") \
    for (int m_ = 0; m_ < 4; ++m_) \
      _Pragma("unroll") \
      for (int n_ = 0; n_ < 2; ++n_) \
        _Pragma("unroll") \
        for (int ks_ = 0; ks_ < 2; ++ks_) \
          acc[(MH) * 4 + m_][(NH) * 2 + n_] = __builtin_amdgcn_mfma_f32_16x16x32_bf16( \
              af[m_][ks_], bfr[(NH) * 2 + n_][ks_], acc[(MH) * 4 + m_][(NH) * 2 + n_], 0, 0, 0); \
    __builtin_amdgcn_s_setprio(0); } while (0)

__global__ __launch_bounds__(512, 2)
void k_gemm(const ushort_t* __restrict__ Xbf, const ushort_t* __restrict__ Wtbf,
            const float* __restrict__ be, const int* __restrict__ assign,
            const int* __restrict__ tgt, float* __restrict__ psum,
            float* __restrict__ tl) {
    __shared__ alignas(16) char smem[136192];
    float* lws = (float*)(smem + 131072);
    int*   lt  = (int*)(smem + 135168);

    const int tid  = threadIdx.x;
    const int wid  = tid >> 6, lane = tid & 63;
    const int q = lane >> 4, ln = lane & 15;
    const int wr = wid >> 2, wc = wid & 3;

    // T1: bijective XCD swizzle (4096 % 8 == 0); rt fastest -> 128 consecutive
    // blocks per XCD share one B column-panel in that XCD's L2.
    const int bid = blockIdx.x;
    const int wg  = ((bid & 7) << 9) | (bid >> 3);
    const int ct  = wg >> 7;        // 0..31 column tile
    const int rt  = wg & 127;       // 0..127 row tile
    const int e   = assign[rt >> 2];
    const size_t eV = (size_t)e * NV;

    // staging source addressing (source-side swizzle: slot ^= row&7)
    const int rquo = tid >> 3;                         // 0..63
    const int scol = ((tid & 7) ^ (rquo & 7)) << 3;    // swizzled k-elem offset
    const ushort_t* gA = Xbf + (size_t)(rt * BM2 + rquo) * ND + scol;
    const ushort_t* gB = Wtbf + (eV + ct * BN2 + rquo) * ND + scol;
    char* ldsW = smem + wid * 1024;                    // wave-uniform dest base
    const int axor = ln & 7;                           // read-side XOR

    // tile's target ids -> LDS (retires with the prologue load batch)
    if (tid < 256) lt[tid] = tgt[rt * BM2 + tid];

    f32x4 acc[8][4];
#pragma unroll
    for (int i = 0; i < 8; ++i)
#pragma unroll
        for (int j = 0; j < 4; ++j) acc[i][j] = (f32x4){0.f, 0.f, 0.f, 0.f};

#define STA(KT, BP, H) do { \
    char* d_ = ldsW + (BP) * 65536 + (H) * 16384; \
    const ushort_t* g_ = gA + (size_t)(H) * 128 * ND + (KT) * 64; \
    g2l16(d_, g_); g2l16(d_ + 8192, g_ + (size_t)64 * ND); } while (0)

#define STB(KT, BP, H) do { \
    char* d_ = ldsW + (BP) * 65536 + 32768 + (H) * 16384; \
    const ushort_t* g_ = gB + (size_t)(H) * 128 * ND + (KT) * 64; \
    g2l16(d_, g_); g2l16(d_ + 8192, g_ + (size_t)64 * ND); } while (0)

#define RDA(BP, MF, KS) \
    (*(const bf16x8*)(smem + (BP) * 65536 + wr * 16384 + \
                      ((MF) * 16 + ln) * 128 + ((((KS) * 4 + q) ^ axor) << 4)))

#define RDB(BP, NF, KS) \
    (*(const bf16x8*)(smem + (BP) * 65536 + 32768 + (wc >> 1) * 16384 + \
                      (((wc & 1) * 64 + (NF) * 16 + ln) * 128) + ((((KS) * 4 + q) ^ axor) << 4)))

    // prologue: kt0 fully + B halves of kt1; wait for kt0 only (vmcnt(4))
    STB(0, 0, 0); STB(0, 0, 1); STA(0, 0, 0); STA(0, 0, 1);
    STB(1, 1, 0); STB(1, 1, 1);
    asm volatile("s_waitcnt vmcnt(4)" ::: "memory");
    __builtin_amdgcn_s_barrier();
    asm volatile("" ::: "memory");

    bf16x8 af[4][2];    // current A quadrant-half (mh0 in Ph1-2, mh1 in Ph3-4)
    bf16x8 bfr[4][2];   // all 4 B n-frags of current K-tile (live Ph1..Ph4)

#pragma unroll
    for (int kt = 0; kt < 8; ++kt) {
        const int p = kt & 1, np = p ^ 1;

        // ---- phase 1: quadrant (0,0) ----
#pragma unroll
        for (int m = 0; m < 4; ++m) { af[m][0] = RDA(p, m, 0); af[m][1] = RDA(p, m, 1); }
#pragma unroll
        for (int n = 0; n < 2; ++n) { bfr[n][0] = RDB(p, n, 0); bfr[n][1] = RDB(p, n, 1); }
        if (kt < 7) STA(kt + 1, np, 0);
        BAR_MID();
        MFMA_QUAD(0, 0);
        BAR_END();

        // ---- phase 2: quadrant (0,1) ----
#pragma unroll
        for (int n = 0; n < 2; ++n) { bfr[2 + n][0] = RDB(p, 2 + n, 0); bfr[2 + n][1] = RDB(p, 2 + n, 1); }
        if (kt < 7) STA(kt + 1, np, 1);
        BAR_MID();
        MFMA_QUAD(0, 1);
        BAR_END();

        // ---- phase 3: quadrant (1,1) ----
#pragma unroll
        for (int m = 0; m < 4; ++m) { af[m][0] = RDA(p, 4 + m, 0); af[m][1] = RDA(p, 4 + m, 1); }
        if (kt < 6) STB(kt + 2, p, 0);
        BAR_MID();
        MFMA_QUAD(1, 1);
        BAR_END();

        // ---- phase 4: quadrant (1,0); K-tile boundary wait ----
        if (kt < 6) STB(kt + 2, p, 1);
        BAR_MID();
        MFMA_QUAD(1, 0);
        if (kt < 6)       { asm volatile("s_waitcnt vmcnt(4)" ::: "memory"); }
        else if (kt == 6) { asm volatile("s_waitcnt vmcnt(0)" ::: "memory"); }
        BAR_END();
    }

    // ---- epilogue: partial sumexp over this tile's 256 cols + target extract ----
    const float LOG2E = 1.44269504088896f;
    int tcv[8][4];
#pragma unroll
    for (int mf = 0; mf < 8; ++mf)
#pragma unroll
        for (int r = 0; r < 4; ++r)
            tcv[mf][r] = lt[wr * 128 + mf * 16 + q * 4 + r];

    float partial[32];
#pragma unroll
    for (int i = 0; i < 32; ++i) partial[i] = 0.f;
#pragma unroll
    for (int nf = 0; nf < 4; ++nf) {
        int col = (ct << 8) + (wc << 6) + nf * 16 + ln;
        float br = be[eV + col];
        float eb = br * LOG2E;
#pragma unroll
        for (int mf = 0; mf < 8; ++mf)
#pragma unroll
            for (int r = 0; r < 4; ++r) {
                partial[mf * 4 + r] += exp2f(fmaf(acc[mf][nf][r], LOG2E, eb));
                if (col == tcv[mf][r])
                    tl[rt * BM2 + wr * 128 + mf * 16 + q * 4 + r] = acc[mf][nf][r] + br;
            }
    }
    // reduce across the 16 column-lanes
#pragma unroll
    for (int i = 0; i < 32; ++i) {
        float pv = partial[i];
        pv += __shfl_xor(pv, 1); pv += __shfl_xor(pv, 2);
        pv += __shfl_xor(pv, 4); pv += __shfl_xor(pv, 8);
        partial[i] = pv;
    }
    if (ln == 0) {
#pragma unroll
        for (int mf = 0; mf < 8; ++mf)
#pragma unroll
            for (int r = 0; r < 4; ++r)
                lws[wid * 128 + mf * 16 + q * 4 + r] = partial[mf * 4 + r];
    }
    __syncthreads();
    if (tid < 256) {
        int wrh = tid >> 7, idx = tid & 127;
        float s = lws[(wrh * 4 + 0) * 128 + idx] + lws[(wrh * 4 + 1) * 128 + idx]
                + lws[(wrh * 4 + 2) * 128 + idx] + lws[(wrh * 4 + 3) * 128 + idx];
        psum[(size_t)ct * NROW + rt * 256 + tid] = s;
    }
#undef STA
#undef STB
#undef RDA
#undef RDB
}

// ---------------- K6: reduce psum -> per-sample nll -> atomic total ----------------
__global__ void k_loss(const float* __restrict__ psum, const float* __restrict__ tl,
                       const int* __restrict__ assign, const int* __restrict__ counts,
                       float* __restrict__ out) {
    int b = blockIdx.x, tid = threadIdx.x;   // 32 blocks x 256 threads
    float acc = 0.f;
#pragma unroll
    for (int j = 0; j < 4; ++j) {
        int t = j * 256 + tid;
        float s = 0.f;
        for (int ct = 0; ct < NCT; ++ct) s += psum[(size_t)ct * NROW + b * NT + t];
        acc += __logf(s) - tl[b * NT + t];
    }
    // block reduce 256 -> 1
    __shared__ float red[4];
    for (int off = 32; off; off >>= 1) acc += __shfl_down(acc, off);
    if ((tid & 63) == 0) red[tid >> 6] = acc;
    __syncthreads();
    if (tid == 0) {
        float nb = red[0] + red[1] + red[2] + red[3];
        float ce = nb * (1.0f / (float)NT);
        atomicAdd(out, ce / (float)counts[assign[b]]);
    }
}

extern "C" void kernel_launch(void* const* d_in, const int* in_sizes, int n_in,
                              void* d_out, int out_size, void* d_ws, size_t ws_size,
                              hipStream_t stream) {
    const float* gate = (const float*)d_in[0];
    const float* X    = (const float*)d_in[1];
    const float* Wg   = (const float*)d_in[2];
    const float* bg   = (const float*)d_in[3];
    const float* We   = (const float*)d_in[4];
    const float* be   = (const float*)d_in[5];
    const int*   tgt  = (const int*)d_in[6];
    float* out = (float*)d_out;

    char* ws = (char*)d_ws;
    ushort_t* Xbf  = (ushort_t*)ws;
    ushort_t* Wtbf = (ushort_t*)(ws + XBF_BYTES);
    float*    psum = (float*)(ws + XBF_BYTES + WT_BYTES);
    float*    tl   = (float*)(ws + XBF_BYTES + WT_BYTES + PSUM_BYTES);
    int*      assign = (int*)(ws + XBF_BYTES + WT_BYTES + PSUM_BYTES + TL_BYTES);
    int*      counts = assign + 32;

    k_convx<<<4096, 256, 0, stream>>>((const float4*)X, Xbf, NB * NT * ND / 4,
                                      gate, Wg, bg, out, assign, counts);
    k_transw<<<dim3(NV / 64, ND / 64, NE), 256, 0, stream>>>(We, Wtbf);
    k_gemm<<<(NROW / BM2) * (NV / BN2), 512, 0, stream>>>(Xbf, Wtbf, be, assign, tgt, psum, tl);
    k_loss<<<NB, 256, 0, stream>>>(psum, tl, assign, counts, out);
}

// Round 5
// 577.214 us; speedup vs baseline: 1.2471x; 1.0541x over previous
//
#include <hip/hip_runtime.h>

// Problem constants
#define NB 32
#define NT 1024
#define ND 512
#define NG 256
#define NE 8
#define NV 8192
#define NROW (NB * NT)   // 32768 output rows

// ---- workspace layout (bytes) ----
#define XBF_BYTES   (33554432)   // NB*NT*ND bf16
#define WT_BYTES    (67108864)   // NE*NV*ND bf16 transposed [e][v][d]
#define PSUM_BYTES  (8388608)    // >= NCT x 32768 rows f32 partial sumexp
#define TL_BYTES    (131072)     // NB*NT f32 target logits

// ---- GEMM geometry: 256x256 tile, BK=64, 8 waves (2Mx4N), 512 threads ----
#define BM2 256
#define BN2 256
#define NCT (NV / BN2)           // 32 column tiles

typedef float f32x4 __attribute__((ext_vector_type(4)));
typedef __bf16 bf16x8 __attribute__((ext_vector_type(8)));
typedef unsigned short ushort8_v __attribute__((ext_vector_type(8)));
typedef unsigned int u32_g __attribute__((address_space(1)));
typedef unsigned int u32_l __attribute__((address_space(3)));
typedef unsigned short ushort_t;

__device__ __forceinline__ void g2l16(void* lds, const void* g) {
    // async global->LDS, 16B per lane; LDS dest = wave-uniform base + lane*16
    __builtin_amdgcn_global_load_lds((const u32_g*)g, (u32_l*)lds, 16, 0, 0);
}

__device__ __forceinline__ unsigned short f2bf(float f) {
    unsigned int u = __float_as_uint(f);
    unsigned int r = (u + 0x7fffu + ((u >> 16) & 1u)) >> 16; // RNE
    return (unsigned short)r;
}

// ---------------- K_prep: transw (bid<8192) + convx (bid>=8192) + router ----------------
// transw: 64x64 tiles, float4 reads, ushort8 writes; LDS cols XOR-rotated by (d>>3)
// so the strided read-back hits 8 distinct banks. convx: grid-stride float4->ushort4.
// Both are independent memory-bound streams; fusing lets them share the HBM pipe.
__global__ __launch_bounds__(256)
void k_prep(const float* __restrict__ We, ushort_t* __restrict__ Wt,
            const float4* __restrict__ X, ushort_t* __restrict__ Xbf, int n4,
            const float* __restrict__ gate, const float* __restrict__ Wg,
            const float* __restrict__ bg, float* __restrict__ out,
            int* __restrict__ assign, int* __restrict__ counts) {
    int bid = blockIdx.x, tid = threadIdx.x;
    if (bid < 8192) {
        // ---- transpose+convert We[e][d][v] -> Wt[e][v][d] bf16 ----
        __shared__ float tile[64][68];   // row stride 68 keeps float4 alignment
        int e = bid >> 10, rem = bid & 1023;
        int d0 = (rem >> 7) << 6;        // 0..7  * 64
        int v0 = (rem & 127) << 6;       // 0..127 * 64
        const float* src = We + (size_t)e * ND * NV + (size_t)d0 * NV + v0;
        int dr = tid >> 4;               // 0..15
        int c4 = tid & 15;               // float4 column index
#pragma unroll
        for (int j = 0; j < 4; ++j) {
            int d = dr + 16 * j;
            float4 v = *(const float4*)(src + (size_t)d * NV + c4 * 4);
            *(float4*)&tile[d][((c4 ^ (d >> 3)) & 15) * 4] = v;
        }
        __syncthreads();
        ushort_t* dst = Wt + (size_t)e * NV * ND + (size_t)v0 * ND + d0;
        int vr = tid >> 3;               // 0..31 (+32 on pass 2)
        int t8 = tid & 7;                // d-chunk; d = t8*8 + i, (d>>3) == t8
#pragma unroll
        for (int j = 0; j < 2; ++j) {
            int v = vr + 32 * j;
            ushort8_v o;
#pragma unroll
            for (int i = 0; i < 8; ++i)
                o[i] = f2bf(tile[t8 * 8 + i][(((v >> 2) ^ t8) & 15) * 4 + (v & 3)]);
            *(ushort8_v*)(dst + (size_t)v * ND + t8 * 8) = o;
        }
    } else {
        if (bid == 8192) {
            // ---- router: 256 threads, one per (b,e) ----
            __shared__ float lg[NB][NE];
            __shared__ int lam[NB];
            int b = tid >> 3, e = tid & 7;
            float acc = bg[e];
            const float* gr = gate + b * NG;
            for (int g = 0; g < NG; ++g) acc = fmaf(gr[g], Wg[g * NE + e], acc);
            lg[b][e] = acc;
            __syncthreads();
            if (tid < NB) {
                float mx = lg[tid][0]; int am = 0;
                for (int j = 1; j < NE; ++j) { float v = lg[tid][j]; if (v > mx) { mx = v; am = j; } }
                float den = 0.f, ex[NE];
                for (int j = 0; j < NE; ++j) { ex[j] = __expf(lg[tid][j] - mx); den += ex[j]; }
                float inv = 1.f / den;
                for (int j = 0; j < NE; ++j) out[1 + NB + tid * NE + j] = ex[j] * inv; // probs
                out[1 + tid] = (float)am;                                             // assignments
                assign[tid] = am;
                lam[tid] = am;
            }
            __syncthreads();
            if (tid == 0) {
                int c[NE] = {0,0,0,0,0,0,0,0};
                for (int i = 0; i < NB; ++i) c[lam[i]]++;
                for (int j = 0; j < NE; ++j) counts[j] = c[j];
                out[0] = 0.f;   // k_loss atomicAdds into this
            }
        }
        // ---- convert X fp32 -> bf16, grid-stride over 4096 virtual blocks ----
        int i = (bid - 8192) * 256 + tid;
        int stride = 4096 * 256;
        for (; i < n4; i += stride) {
            float4 v = X[i];
            ushort4 o;
            o.x = f2bf(v.x); o.y = f2bf(v.y); o.z = f2bf(v.z); o.w = f2bf(v.w);
            ((ushort4*)Xbf)[i] = o;
        }
    }
}

// ---------------- K4: fused GEMM + exp partial-sum + target-logit extract ----------------
// R1-verified 256x256 / BK=64 / 8-wave / 4-quadrant-phase pipeline (T1+T2+T3/T4+T5).
// One tile per block, grid 4096 (16 generations). Prologue additionally stages the
// tile's be slice (1KB, wave 0) and target ids (1KB, wave 1) into LDS via g2l16 —
// issued FIRST so the existing vmcnt(4) proves they landed. Epilogue is
// global-load-free; target extraction is a separate 32-compare pass (execz-skipped),
// NOT inside the exp2 hot loop (R4's 30us mistake).
//
// LDS (134 KiB): dbuf p at p*65536 { A[256][64] bf16 ; B at +32768 },
// lws at 131072 (4KB), lbe at 135168 (1KB), lt at 136192 (1KB).

#define BAR_MID() do { \
    asm volatile("" ::: "memory"); \
    __builtin_amdgcn_s_barrier(); \
    asm volatile("s_waitcnt lgkmcnt(0)" ::: "memory"); \
    __builtin_amdgcn_sched_barrier(0); } while (0)

#define BAR_END() do { \
    asm volatile("" ::: "memory"); \
    __builtin_amdgcn_s_barrier(); \
    asm volatile("" ::: "memory"); } while (0)

#define MFMA_QUAD(MH, NH) do { \
    __builtin_amdgcn_s_setprio(1); \
    _Pragma("unroll") \
    for (int m_ = 0; m_ < 4; ++m_) \
      _Pragma("unroll") \
      for (int n_ = 0; n_ < 2; ++n_) \
        _Pragma("unroll") \
        for (int ks_ = 0; ks_ < 2; ++ks_) \
          acc[(MH) * 4 + m_][(NH) * 2 + n_] = __builtin_amdgcn_mfma_f32_16x16x32_bf16( \
              af[m_][ks_], bfr[(NH) * 2 + n_][ks_], acc[(MH) * 4 + m_][(NH) * 2 + n_], 0, 0, 0); \
    __builtin_amdgcn_s_setprio(0); } while (0)

__global__ __launch_bounds__(512, 2)
void k_gemm(const ushort_t* __restrict__ Xbf, const ushort_t* __restrict__ Wtbf,
            const float* __restrict__ be, const int* __restrict__ assign,
            const int* __restrict__ tgt, float* __restrict__ psum,
            float* __restrict__ tl) {
    __shared__ alignas(16) char smem[137216];
    float* lws = (float*)(smem + 131072);
    float* lbe = (float*)(smem + 135168);
    int*   lt  = (int*)(smem + 136192);

    const int tid  = threadIdx.x;
    const int wid  = tid >> 6, lane = tid & 63;
    const int q = lane >> 4, ln = lane & 15;
    const int wr = wid >> 2, wc = wid & 3;

    // T1: bijective XCD swizzle (4096 % 8 == 0); rt fastest -> 128 consecutive
    // blocks per XCD share one B column-panel in that XCD's L2.
    const int bid = blockIdx.x;
    const int wg  = ((bid & 7) << 9) | (bid >> 3);
    const int ct  = wg >> 7;        // 0..31 column tile
    const int rt  = wg & 127;       // 0..127 row tile
    const int e   = assign[rt >> 2];
    const size_t eV = (size_t)e * NV;

    // staging source addressing (source-side swizzle: slot ^= row&7)
    const int rquo = tid >> 3;                         // 0..63
    const int scol = ((tid & 7) ^ (rquo & 7)) << 3;    // swizzled k-elem offset
    const ushort_t* gA = Xbf + (size_t)(rt * BM2 + rquo) * ND + scol;
    const ushort_t* gB = Wtbf + (eV + ct * BN2 + rquo) * ND + scol;
    char* ldsW = smem + wid * 1024;                    // wave-uniform dest base
    const int axor = ln & 7;                           // read-side XOR

    f32x4 acc[8][4];
#pragma unroll
    for (int i = 0; i < 8; ++i)
#pragma unroll
        for (int j = 0; j < 4; ++j) acc[i][j] = (f32x4){0.f, 0.f, 0.f, 0.f};

#define STA(KT, BP, H) do { \
    char* d_ = ldsW + (BP) * 65536 + (H) * 16384; \
    const ushort_t* g_ = gA + (size_t)(H) * 128 * ND + (KT) * 64; \
    g2l16(d_, g_); g2l16(d_ + 8192, g_ + (size_t)64 * ND); } while (0)

#define STB(KT, BP, H) do { \
    char* d_ = ldsW + (BP) * 65536 + 32768 + (H) * 16384; \
    const ushort_t* g_ = gB + (size_t)(H) * 128 * ND + (KT) * 64; \
    g2l16(d_, g_); g2l16(d_ + 8192, g_ + (size_t)64 * ND); } while (0)

#define RDA(BP, MF, KS) \
    (*(const bf16x8*)(smem + (BP) * 65536 + wr * 16384 + \
                      ((MF) * 16 + ln) * 128 + ((((KS) * 4 + q) ^ axor) << 4)))

#define RDB(BP, NF, KS) \
    (*(const bf16x8*)(smem + (BP) * 65536 + 32768 + (wc >> 1) * 16384 + \
                      (((wc & 1) * 64 + (NF) * 16 + ln) * 128) + ((((KS) * 4 + q) ^ axor) << 4)))

    // aux stages FIRST (oldest in vm queue -> covered by the vmcnt(4) below):
    // wave 0: be slice (256 f32 = 1KB); wave 1: target ids (256 i32 = 1KB)
    if (wid == 0) g2l16(smem + 135168, be + eV + (ct << 8) + (lane << 2));
    if (wid == 1) g2l16(smem + 136192, tgt + rt * BM2 + (lane << 2));

    // prologue: kt0 fully + B halves of kt1; wait for kt0 only (vmcnt(4))
    STB(0, 0, 0); STB(0, 0, 1); STA(0, 0, 0); STA(0, 0, 1);
    STB(1, 1, 0); STB(1, 1, 1);
    asm volatile("s_waitcnt vmcnt(4)" ::: "memory");
    __builtin_amdgcn_s_barrier();
    asm volatile("" ::: "memory");

    bf16x8 af[4][2];    // current A quadrant-half (mh0 in Ph1-2, mh1 in Ph3-4)
    bf16x8 bfr[4][2];   // all 4 B n-frags of current K-tile (live Ph1..Ph4)

#pragma unroll
    for (int kt = 0; kt < 8; ++kt) {
        const int p = kt & 1, np = p ^ 1;

        // ---- phase 1: quadrant (0,0) ----
#pragma unroll
        for (int m = 0; m < 4; ++m) { af[m][0] = RDA(p, m, 0); af[m][1] = RDA(p, m, 1); }
#pragma unroll
        for (int n = 0; n < 2; ++n) { bfr[n][0] = RDB(p, n, 0); bfr[n][1] = RDB(p, n, 1); }
        if (kt < 7) STA(kt + 1, np, 0);
        BAR_MID();
        MFMA_QUAD(0, 0);
        BAR_END();

        // ---- phase 2: quadrant (0,1) ----
#pragma unroll
        for (int n = 0; n < 2; ++n) { bfr[2 + n][0] = RDB(p, 2 + n, 0); bfr[2 + n][1] = RDB(p, 2 + n, 1); }
        if (kt < 7) STA(kt + 1, np, 1);
        BAR_MID();
        MFMA_QUAD(0, 1);
        BAR_END();

        // ---- phase 3: quadrant (1,1) ----
#pragma unroll
        for (int m = 0; m < 4; ++m) { af[m][0] = RDA(p, 4 + m, 0); af[m][1] = RDA(p, 4 + m, 1); }
        if (kt < 6) STB(kt + 2, p, 0);
        BAR_MID();
        MFMA_QUAD(1, 1);
        BAR_END();

        // ---- phase 4: quadrant (1,0); K-tile boundary wait ----
        if (kt < 6) STB(kt + 2, p, 1);
        BAR_MID();
        MFMA_QUAD(1, 0);
        if (kt < 6)       { asm volatile("s_waitcnt vmcnt(4)" ::: "memory"); }
        else if (kt == 6) { asm volatile("s_waitcnt vmcnt(0)" ::: "memory"); }
        BAR_END();
    }

    // ---- epilogue A: partial sumexp over this tile's 256 cols (LDS-only be) ----
    const float LOG2E = 1.44269504088896f;
    float lbev[4];
#pragma unroll
    for (int nf = 0; nf < 4; ++nf) lbev[nf] = lbe[(wc << 6) + nf * 16 + ln];

    float partial[32];
#pragma unroll
    for (int i = 0; i < 32; ++i) partial[i] = 0.f;
#pragma unroll
    for (int nf = 0; nf < 4; ++nf) {
        float eb = lbev[nf] * LOG2E;
#pragma unroll
        for (int mf = 0; mf < 8; ++mf)
#pragma unroll
            for (int r = 0; r < 4; ++r)
                partial[mf * 4 + r] += exp2f(fmaf(acc[mf][nf][r], LOG2E, eb));
    }

    // ---- epilogue B: target-logit extract (one guarded pass, outside hot loop) ----
    {
        const int cb = (ct << 8) + (wc << 6);
#pragma unroll
        for (int mf = 0; mf < 8; ++mf)
#pragma unroll
            for (int r = 0; r < 4; ++r) {
                int local = lt[wr * 128 + mf * 16 + q * 4 + r] - cb;
                if ((unsigned)local < 64u && (local & 15) == ln) {
                    int nfi = local >> 4;                     // 0..3, static select below
                    float v = (nfi == 0) ? acc[mf][0][r]
                            : (nfi == 1) ? acc[mf][1][r]
                            : (nfi == 2) ? acc[mf][2][r]
                            :              acc[mf][3][r];
                    tl[rt * BM2 + wr * 128 + mf * 16 + q * 4 + r] = v + lbe[(wc << 6) + local];
                }
            }
    }

    // reduce across the 16 column-lanes
#pragma unroll
    for (int i = 0; i < 32; ++i) {
        float pv = partial[i];
        pv += __shfl_xor(pv, 1); pv += __shfl_xor(pv, 2);
        pv += __shfl_xor(pv, 4); pv += __shfl_xor(pv, 8);
        partial[i] = pv;
    }
    if (ln == 0) {
#pragma unroll
        for (int mf = 0; mf < 8; ++mf)
#pragma unroll
            for (int r = 0; r < 4; ++r)
                lws[wid * 128 + mf * 16 + q * 4 + r] = partial[mf * 4 + r];
    }
    __syncthreads();
    if (tid < 256) {
        int wrh = tid >> 7, idx = tid & 127;
        float s = lws[(wrh * 4 + 0) * 128 + idx] + lws[(wrh * 4 + 1) * 128 + idx]
                + lws[(wrh * 4 + 2) * 128 + idx] + lws[(wrh * 4 + 3) * 128 + idx];
        psum[(size_t)ct * NROW + rt * 256 + tid] = s;
    }
#undef STA
#undef STB
#undef RDA
#undef RDB
}

// ---------------- K6: reduce psum -> per-sample nll -> atomic total ----------------
__global__ void k_loss(const float* __restrict__ psum, const float* __restrict__ tl,
                       const int* __restrict__ assign, const int* __restrict__ counts,
                       float* __restrict__ out) {
    int b = blockIdx.x, tid = threadIdx.x;   // 32 blocks x 256 threads
    float acc = 0.f;
#pragma unroll
    for (int j = 0; j < 4; ++j) {
        int t = j * 256 + tid;
        float s = 0.f;
        for (int ct = 0; ct < NCT; ++ct) s += psum[(size_t)ct * NROW + b * NT + t];
        acc += __logf(s) - tl[b * NT + t];
    }
    // block reduce 256 -> 1
    __shared__ float red[4];
    for (int off = 32; off; off >>= 1) acc += __shfl_down(acc, off);
    if ((tid & 63) == 0) red[tid >> 6] = acc;
    __syncthreads();
    if (tid == 0) {
        float nb = red[0] + red[1] + red[2] + red[3];
        float ce = nb * (1.0f / (float)NT);
        atomicAdd(out, ce / (float)counts[assign[b]]);
    }
}

extern "C" void kernel_launch(void* const* d_in, const int* in_sizes, int n_in,
                              void* d_out, int out_size, void* d_ws, size_t ws_size,
                              hipStream_t stream) {
    const float* gate = (const float*)d_in[0];
    const float* X    = (const float*)d_in[1];
    const float* Wg   = (const float*)d_in[2];
    const float* bg   = (const float*)d_in[3];
    const float* We   = (const float*)d_in[4];
    const float* be   = (const float*)d_in[5];
    const int*   tgt  = (const int*)d_in[6];
    float* out = (float*)d_out;

    char* ws = (char*)d_ws;
    ushort_t* Xbf  = (ushort_t*)ws;
    ushort_t* Wtbf = (ushort_t*)(ws + XBF_BYTES);
    float*    psum = (float*)(ws + XBF_BYTES + WT_BYTES);
    float*    tl   = (float*)(ws + XBF_BYTES + WT_BYTES + PSUM_BYTES);
    int*      assign = (int*)(ws + XBF_BYTES + WT_BYTES + PSUM_BYTES + TL_BYTES);
    int*      counts = assign + 32;

    k_prep<<<12288, 256, 0, stream>>>(We, Wtbf, (const float4*)X, Xbf, NB * NT * ND / 4,
                                      gate, Wg, bg, out, assign, counts);
    k_gemm<<<(NROW / BM2) * (NV / BN2), 512, 0, stream>>>(Xbf, Wtbf, be, assign, tgt, psum, tl);
    k_loss<<<NB, 256, 0, stream>>>(psum, tl, assign, counts, out);
}